// Round 5
// baseline (606.254 us; speedup 1.0000x reference)
//
#include <hip/hip_runtime.h>

#define H_DIM 2048
#define DMID  1024
#define DOUT  256
#define NTOK  32768
#define NIMG  32

typedef __attribute__((ext_vector_type(8))) __bf16 bf16x8;
typedef __attribute__((ext_vector_type(4))) float f32x4;

__device__ __forceinline__ unsigned f2bf(float f) {
  unsigned u = __builtin_bit_cast(unsigned, f);
  u += 0x7fff + ((u >> 16) & 1);   // RNE
  return u >> 16;
}

// async global->LDS, 16B per lane. LDS dest must be wave-uniform base + lane*16.
__device__ __forceinline__ void async_copy16(const void* gptr, void* lptr) {
  auto g = (const __attribute__((address_space(1))) unsigned int*)(unsigned long long)gptr;
  unsigned loff = (unsigned)(unsigned long long)lptr;
  auto l = (__attribute__((address_space(3))) unsigned int*)loff;
  __builtin_amdgcn_global_load_lds(g, l, 16, 0, 0);
}

// One kernel converts both weight matrices (W1b and W2b are adjacent in ws).
__global__ void convert_ws(const float* __restrict__ W1, const float* __restrict__ W2,
                           unsigned short* __restrict__ dst, int n4_1, int n4_tot) {
  int i = blockIdx.x * blockDim.x + threadIdx.x;
  if (i >= n4_tot) return;
  float4 f = (i < n4_1) ? ((const float4*)W1)[i] : ((const float4*)W2)[i - n4_1];
  ushort4 o;
  o.x = (unsigned short)f2bf(f.x);
  o.y = (unsigned short)f2bf(f.y);
  o.z = (unsigned short)f2bf(f.z);
  o.w = (unsigned short)f2bf(f.w);
  ((ushort4*)dst)[i] = o;
}

// Fully fused single GEMM kernel:
//   H-tile = mish(gather(A32)@W1^T + b1)  (A gathered+converted inline, T14 split)
//   out[seg[m],o] += H-tile @ W2slice^T  (+ b2 once, gated on n0==0)
// No Abuf, no gather kernel, no Hbuf: A read as fp32 exactly once per XCD.
__global__ __launch_bounds__(256, 2) void gemm_fused(
    const float* __restrict__ A32, const unsigned short* __restrict__ B,
    const float* __restrict__ b1, const int* __restrict__ flat_idx,
    const unsigned short* __restrict__ W2b, const float* __restrict__ b2,
    const int* __restrict__ seg, float* __restrict__ out) {
  __shared__ __align__(16) unsigned short As[2][128 * 64];  // K-loop A dbuf; epilogue: H 128x128
  __shared__ __align__(16) unsigned short Bs[2][128 * 64];  // K-loop B dbuf; epilogue: W2 128x128 half
  __shared__ int rowmap[128];
  __shared__ int segl[128];

  const int tid = threadIdx.x;
  const int lane = tid & 63;
  const int wave = tid >> 6;
  const int wm = wave >> 1, wn = wave & 1;
  // XCD-clustered decomposition: 8 sibling n-blocks of one m-panel adjacent on one XCD,
  // so the fp32 A-panel is fetched from HBM once and L2-hit 7 times.
  const int bid = blockIdx.x;
  const int xcd = bid & 7;
  const int jj0 = bid >> 3;
  const int m0 = (xcd * 32 + (jj0 >> 3)) * 128;
  const int n0 = (jj0 & 7) * 128;

  if (tid < 128) rowmap[tid] = flat_idx[m0 + tid];
  __syncthreads();

  // Hoist per-thread A addresses (row fixed across K-tiles).
  size_t abase[4];
#pragma unroll
  for (int it = 0; it < 4; ++it) {
    int id = it * 256 + tid;
    int row = id >> 3, c8 = id & 7;
    int gc8 = c8 ^ (row & 7);
    abase[it] = (size_t)rowmap[row] * H_DIM + gc8 * 8;
  }

  auto stageB = [&](int b, int t) {
    int kk = t * 64;
#pragma unroll
    for (int it = 0; it < 4; ++it) {
      int id = it * 256 + tid;
      int row = id >> 3, c8 = id & 7;
      int gc8 = c8 ^ (row & 7);
      async_copy16(B + (size_t)(n0 + row) * H_DIM + kk + gc8 * 8, &Bs[b][id * 8]);
    }
  };

  // T14 split: loadA issues global loads to regs (before MFMA);
  // packA converts+writes LDS (after MFMA) — HBM latency hides under compute.
  float4 fa[4], fb[4];
  auto loadA = [&](int t) {
    int kk = t * 64;
#pragma unroll
    for (int it = 0; it < 4; ++it) {
      const float* src = A32 + abase[it] + kk;
      fa[it] = *(const float4*)src;
      fb[it] = *(const float4*)(src + 4);
    }
  };
  auto packA = [&](int b) {
#pragma unroll
    for (int it = 0; it < 4; ++it) {
      int id = it * 256 + tid;
      uint4 pk;
      pk.x = (f2bf(fa[it].y) << 16) | f2bf(fa[it].x);
      pk.y = (f2bf(fa[it].w) << 16) | f2bf(fa[it].z);
      pk.z = (f2bf(fb[it].y) << 16) | f2bf(fb[it].x);
      pk.w = (f2bf(fb[it].w) << 16) | f2bf(fb[it].z);
      *(uint4*)&As[b][id * 8] = pk;
    }
  };

  f32x4 acc[4][4];
#pragma unroll
  for (int i = 0; i < 4; i++)
#pragma unroll
    for (int jj = 0; jj < 4; jj++) acc[i][jj] = f32x4{0.f, 0.f, 0.f, 0.f};

  constexpr int NT = H_DIM / 64;  // 32 K-tiles, 2-phase pipelined
  stageB(0, 0);
  loadA(0);
  packA(0);
  __syncthreads();
  int cur = 0;
  for (int t = 0; t < NT; ++t) {
    if (t + 1 < NT) {
      stageB(cur ^ 1, t + 1);  // async DMA, drained by end-of-iter barrier
      loadA(t + 1);            // issue global loads now; consumed after MFMA
    }
#pragma unroll
    for (int ks = 0; ks < 2; ++ks) {
      bf16x8 af[4], bg[4];
#pragma unroll
      for (int mt = 0; mt < 4; ++mt) {
        int r = wm * 64 + mt * 16 + (lane & 15);
        int jj = (lane >> 4) + ks * 4;
        af[mt] = *(const bf16x8*)&As[cur][r * 64 + ((jj ^ (r & 7)) << 3)];
      }
#pragma unroll
      for (int nt = 0; nt < 4; ++nt) {
        int r = wn * 64 + nt * 16 + (lane & 15);
        int jj = (lane >> 4) + ks * 4;
        bg[nt] = *(const bf16x8*)&Bs[cur][r * 64 + ((jj ^ (r & 7)) << 3)];
      }
#pragma unroll
      for (int mt = 0; mt < 4; ++mt)
#pragma unroll
        for (int nt = 0; nt < 4; ++nt)
          acc[mt][nt] = __builtin_amdgcn_mfma_f32_16x16x32_bf16(
              af[mt], bg[nt], acc[mt][nt], 0, 0, 0);
    }
    if (t + 1 < NT) packA(cur ^ 1);  // vmcnt wait lands here, after MFMA
    __syncthreads();
    cur ^= 1;
  }

  // ================= fused epilogue =================
  // Hl: 128(m) x 128(k') bf16, swizzled [m*128 + ((g^(m&7))<<3) + (k&7)], g=k>>3
  // W2s: 128(o-half) x 128(k') bf16, same swizzle, staged async per 128-o half.
  unsigned short* Hl  = &As[0][0];   // 32 KiB (spans both dbuf halves)
  unsigned short* W2s = &Bs[0][0];   // 32 KiB

  if (tid < 128) segl[tid] = seg[m0 + tid];

  auto stageW2 = [&](int h) {
#pragma unroll
    for (int it = 0; it < 8; ++it) {
      int id = it * 256 + tid;            // 0..2047 granules of 16B
      int row = id >> 4, c16 = id & 15;
      int g = c16 ^ (row & 7);            // involution on low 3 bits
      async_copy16(W2b + (size_t)(h * 128 + row) * DMID + n0 + g * 8, &W2s[id * 8]);
    }
  };
  stageW2(0);

  // mish -> bf16 -> Hl
#pragma unroll
  for (int nt = 0; nt < 4; ++nt) {
    int kc = wn * 64 + nt * 16 + (lane & 15);   // local k' in [0,128)
    float bias = b1[n0 + kc];
#pragma unroll
    for (int mt = 0; mt < 4; ++mt) {
#pragma unroll
      for (int r = 0; r < 4; ++r) {
        int ml = wm * 64 + mt * 16 + ((lane >> 4) << 2) + r;
        float x = acc[mt][nt][r] + bias;
        // mish(x) = x*tanh(softplus(x)) = x*u/(u+2), u = t(t+2), t = e^x
        float t = __expf(x);
        float u = t * (t + 2.f);
        float y = (x < 10.f) ? x * u * __builtin_amdgcn_rcpf(u + 2.f) : x;
        int g = kc >> 3;
        Hl[ml * 128 + ((g ^ (ml & 7)) << 3) + (kc & 7)] = (unsigned short)f2bf(y);
      }
    }
  }
  __syncthreads();  // Hl written; W2 half-0 DMA drained; segl visible

  int s0 = segl[0], s1 = segl[127];
  int myseg[16];
#pragma unroll
  for (int mt = 0; mt < 4; ++mt)
#pragma unroll
    for (int r = 0; r < 4; ++r)
      myseg[mt * 4 + r] = segl[wm * 64 + mt * 16 + ((lane >> 4) << 2) + r];

  for (int h = 0; h < 2; ++h) {
    f32x4 acc2[4][4];
#pragma unroll
    for (int i = 0; i < 4; i++)
#pragma unroll
      for (int jj = 0; jj < 4; jj++) acc2[i][jj] = f32x4{0.f, 0.f, 0.f, 0.f};

#pragma unroll
    for (int ks = 0; ks < 4; ++ks) {
      bf16x8 af[4], bg[4];
#pragma unroll
      for (int mt = 0; mt < 4; ++mt) {
        int m = wm * 64 + mt * 16 + (lane & 15);
        int jj = (lane >> 4) + ks * 4;
        af[mt] = *(const bf16x8*)&Hl[m * 128 + ((jj ^ (m & 7)) << 3)];
      }
#pragma unroll
      for (int ot = 0; ot < 4; ++ot) {
        int o = wn * 64 + ot * 16 + (lane & 15);
        int jj = (lane >> 4) + ks * 4;
        bg[ot] = *(const bf16x8*)&W2s[o * 128 + ((jj ^ (o & 7)) << 3)];
      }
#pragma unroll
      for (int mt = 0; mt < 4; ++mt)
#pragma unroll
        for (int ot = 0; ot < 4; ++ot)
          acc2[mt][ot] = __builtin_amdgcn_mfma_f32_16x16x32_bf16(
              af[mt], bg[ot], acc2[mt][ot], 0, 0, 0);
    }

    if (h == 0) {
      __syncthreads();  // all waves done reading W2s half-0
      stageW2(1);       // prefetch half-1 under the atomics below
    }

    // segment-pooled reduction for this o-half (b2 added once: only n0==0 blocks)
    if (s0 == s1) {
      float* op = out + s0 * DOUT + h * 128;
#pragma unroll
      for (int ot = 0; ot < 4; ++ot) {
        int oc = wn * 64 + ot * 16 + (lane & 15);
        float s = (n0 == 0) ? 16.f * b2[h * 128 + oc] : 0.f;
#pragma unroll
        for (int mt = 0; mt < 4; ++mt)
#pragma unroll
          for (int r = 0; r < 4; ++r) s += acc2[mt][ot][r];
        s += __shfl_xor(s, 16);
        s += __shfl_xor(s, 32);
        if ((lane >> 4) == 0) atomicAdd(&op[oc], s);
      }
    } else {
      for (int sgi = s0; sgi <= s1; ++sgi) {
#pragma unroll
        for (int ot = 0; ot < 4; ++ot) {
          int oc = wn * 64 + ot * 16 + (lane & 15);
          float bias2 = (n0 == 0) ? b2[h * 128 + oc] : 0.f;
          float v = 0.f;
#pragma unroll
          for (int mt = 0; mt < 4; ++mt)
#pragma unroll
            for (int r = 0; r < 4; ++r)
              v += (myseg[mt * 4 + r] == sgi) ? (acc2[mt][ot][r] + bias2) : 0.f;
          v += __shfl_xor(v, 16);
          v += __shfl_xor(v, 32);
          if ((lane >> 4) == 0) atomicAdd(&out[sgi * DOUT + h * 128 + oc], v);
        }
      }
    }

    if (h == 0) __syncthreads();  // W2 half-1 DMA drained before h=1 compute
  }
}

extern "C" void kernel_launch(void* const* d_in, const int* in_sizes, int n_in,
                              void* d_out, int out_size, void* d_ws, size_t ws_size,
                              hipStream_t stream) {
  const float* hidden = (const float*)d_in[0];
  const float* W1 = (const float*)d_in[1];
  const float* b1 = (const float*)d_in[2];
  const float* W2 = (const float*)d_in[3];
  const float* b2 = (const float*)d_in[4];
  const int* flat_idx = (const int*)d_in[5];
  const int* seg = (const int*)d_in[6];
  float* out = (float*)d_out;

  unsigned short* W1b = (unsigned short*)d_ws;       // 1024*2048*2 = 4 MiB
  unsigned short* W2b = W1b + (size_t)DMID * H_DIM;  // 256*1024*2  = 512 KiB

  size_t need = ((size_t)DMID * H_DIM + (size_t)DOUT * DMID) * 2;
  if (ws_size < need) return;

  constexpr int N4_1 = DMID * H_DIM / 4;
  constexpr int N4_T = N4_1 + DOUT * DMID / 4;

  hipMemsetAsync(d_out, 0, (size_t)NIMG * DOUT * sizeof(float), stream);
  convert_ws<<<(N4_T + 255) / 256, 256, 0, stream>>>(W1, W2, W1b, N4_1, N4_T);
  gemm_fused<<<2048, 256, 0, stream>>>(hidden, W1b, b1, flat_idx, W2b, b2, seg, out);
}

// Round 6
// 567.551 us; speedup vs baseline: 1.0682x; 1.0682x over previous
//
#include <hip/hip_runtime.h>

#define H_DIM 2048
#define DMID  1024
#define DOUT  256
#define NTOK  32768
#define NIMG  32

typedef __attribute__((ext_vector_type(8))) __bf16 bf16x8;
typedef __attribute__((ext_vector_type(4))) float f32x4;

__device__ __forceinline__ unsigned f2bf(float f) {
  unsigned u = __builtin_bit_cast(unsigned, f);
  u += 0x7fff + ((u >> 16) & 1);   // RNE
  return u >> 16;
}

// Native packed f32->bf16 (RNE) — one VOP3 instead of ~6 VALU ops per pair.
__device__ __forceinline__ unsigned cvtpk(float lo, float hi) {
  unsigned r;
  asm("v_cvt_pk_bf16_f32 %0, %1, %2" : "=v"(r) : "v"(lo), "v"(hi));
  return r;
}

// async global->LDS, 16B per lane. LDS dest must be wave-uniform base + lane*16.
__device__ __forceinline__ void async_copy16(const void* gptr, void* lptr) {
  auto g = (const __attribute__((address_space(1))) unsigned int*)(unsigned long long)gptr;
  unsigned loff = (unsigned)(unsigned long long)lptr;
  auto l = (__attribute__((address_space(3))) unsigned int*)loff;
  __builtin_amdgcn_global_load_lds(g, l, 16, 0, 0);
}

// One kernel converts both weight matrices (W1b and W2b are adjacent in ws).
__global__ void convert_ws(const float* __restrict__ W1, const float* __restrict__ W2,
                           unsigned short* __restrict__ dst, int n4_1, int n4_tot) {
  int i = blockIdx.x * blockDim.x + threadIdx.x;
  if (i >= n4_tot) return;
  float4 f = (i < n4_1) ? ((const float4*)W1)[i] : ((const float4*)W2)[i - n4_1];
  ushort4 o;
  o.x = (unsigned short)f2bf(f.x);
  o.y = (unsigned short)f2bf(f.y);
  o.z = (unsigned short)f2bf(f.z);
  o.w = (unsigned short)f2bf(f.w);
  ((ushort4*)dst)[i] = o;
}

// Fully fused single GEMM kernel:
//   H-tile = mish(gather(A32)@W1^T + b1)  (A gathered+converted inline, T14 split)
//   out[seg[m],o] += H-tile @ W2slice^T  (+ b2 once, gated on n0==0)
// T14 fix vs prior round: sched_barrier(0) fences pin the A global loads ABOVE
// the MFMA block and the pack/ds_write BELOW it — without them hipcc sinks the
// loads to the pack site (VGPR stayed 88 => loads were sunk => full latency
// exposed, MfmaUtil 18%). Pack uses v_cvt_pk_bf16_f32 (16 instrs vs ~96).
__global__ __launch_bounds__(256, 2) void gemm_fused(
    const float* __restrict__ A32, const unsigned short* __restrict__ B,
    const float* __restrict__ b1, const int* __restrict__ flat_idx,
    const unsigned short* __restrict__ W2b, const float* __restrict__ b2,
    const int* __restrict__ seg, float* __restrict__ out) {
  __shared__ __align__(16) unsigned short As[2][128 * 64];  // K-loop A dbuf; epilogue: H 128x128
  __shared__ __align__(16) unsigned short Bs[2][128 * 64];  // K-loop B dbuf; epilogue: W2 128x128 half
  __shared__ int rowmap[128];
  __shared__ int segl[128];

  const int tid = threadIdx.x;
  const int lane = tid & 63;
  const int wave = tid >> 6;
  const int wm = wave >> 1, wn = wave & 1;
  // XCD-clustered decomposition: 8 sibling n-blocks of one m-panel adjacent on one XCD,
  // so the fp32 A-panel is fetched from HBM once and L2-hit 7 times.
  const int bid = blockIdx.x;
  const int xcd = bid & 7;
  const int jj0 = bid >> 3;
  const int m0 = (xcd * 32 + (jj0 >> 3)) * 128;
  const int n0 = (jj0 & 7) * 128;

  if (tid < 128) rowmap[tid] = flat_idx[m0 + tid];
  __syncthreads();

  // Hoist per-thread A addresses (row fixed across K-tiles).
  size_t abase[4];
#pragma unroll
  for (int it = 0; it < 4; ++it) {
    int id = it * 256 + tid;
    int row = id >> 3, c8 = id & 7;
    int gc8 = c8 ^ (row & 7);
    abase[it] = (size_t)rowmap[row] * H_DIM + gc8 * 8;
  }

  auto stageB = [&](int b, int t) {
    int kk = t * 64;
#pragma unroll
    for (int it = 0; it < 4; ++it) {
      int id = it * 256 + tid;
      int row = id >> 3, c8 = id & 7;
      int gc8 = c8 ^ (row & 7);
      async_copy16(B + (size_t)(n0 + row) * H_DIM + kk + gc8 * 8, &Bs[b][id * 8]);
    }
  };

  // T14 split: loadA issues global loads to regs (before MFMA);
  // packA converts+writes LDS (after MFMA) — HBM latency hides under compute.
  float4 fa[4], fb[4];
  auto loadA = [&](int t) {
    int kk = t * 64;
#pragma unroll
    for (int it = 0; it < 4; ++it) {
      const float* src = A32 + abase[it] + kk;
      fa[it] = *(const float4*)src;
      fb[it] = *(const float4*)(src + 4);
    }
  };
  auto packA = [&](int b) {
#pragma unroll
    for (int it = 0; it < 4; ++it) {
      int id = it * 256 + tid;
      uint4 pk;
      pk.x = cvtpk(fa[it].x, fa[it].y);
      pk.y = cvtpk(fa[it].z, fa[it].w);
      pk.z = cvtpk(fb[it].x, fb[it].y);
      pk.w = cvtpk(fb[it].z, fb[it].w);
      *(uint4*)&As[b][id * 8] = pk;
    }
  };

  f32x4 acc[4][4];
#pragma unroll
  for (int i = 0; i < 4; i++)
#pragma unroll
    for (int jj = 0; jj < 4; jj++) acc[i][jj] = f32x4{0.f, 0.f, 0.f, 0.f};

  constexpr int NT = H_DIM / 64;  // 32 K-tiles, 2-phase pipelined
  loadA(0);
  stageB(0, 0);
  packA(0);
  __syncthreads();
  int cur = 0;
  for (int t = 0; t < NT; ++t) {
    if (t + 1 < NT) {
      loadA(t + 1);            // issue register loads first (deepest latency)
      stageB(cur ^ 1, t + 1);  // fire-and-forget DMA (drained at the barrier)
    }
    __builtin_amdgcn_sched_barrier(0);  // loads stay issued ABOVE the MFMA block
#pragma unroll
    for (int ks = 0; ks < 2; ++ks) {
      bf16x8 af[4], bg[4];
#pragma unroll
      for (int mt = 0; mt < 4; ++mt) {
        int r = wm * 64 + mt * 16 + (lane & 15);
        int jj = (lane >> 4) + ks * 4;
        af[mt] = *(const bf16x8*)&As[cur][r * 64 + ((jj ^ (r & 7)) << 3)];
      }
#pragma unroll
      for (int nt = 0; nt < 4; ++nt) {
        int r = wn * 64 + nt * 16 + (lane & 15);
        int jj = (lane >> 4) + ks * 4;
        bg[nt] = *(const bf16x8*)&Bs[cur][r * 64 + ((jj ^ (r & 7)) << 3)];
      }
#pragma unroll
      for (int mt = 0; mt < 4; ++mt)
#pragma unroll
        for (int nt = 0; nt < 4; ++nt)
          acc[mt][nt] = __builtin_amdgcn_mfma_f32_16x16x32_bf16(
              af[mt], bg[nt], acc[mt][nt], 0, 0, 0);
    }
    __builtin_amdgcn_sched_barrier(0);  // pack (and its vmcnt wait) stays BELOW MFMA
    if (t + 1 < NT) packA(cur ^ 1);     // waits vmcnt(4): A loads only, B-DMA in flight
    __syncthreads();
    cur ^= 1;
  }

  // ================= fused epilogue =================
  // Hl: 128(m) x 128(k') bf16, swizzled [m*128 + ((g^(m&7))<<3) + (k&7)], g=k>>3
  // W2s: 128(o-half) x 128(k') bf16, same swizzle, staged async per 128-o half.
  unsigned short* Hl  = &As[0][0];   // 32 KiB (spans both dbuf halves)
  unsigned short* W2s = &Bs[0][0];   // 32 KiB

  if (tid < 128) segl[tid] = seg[m0 + tid];

  auto stageW2 = [&](int h) {
#pragma unroll
    for (int it = 0; it < 8; ++it) {
      int id = it * 256 + tid;            // 0..2047 granules of 16B
      int row = id >> 4, c16 = id & 15;
      int g = c16 ^ (row & 7);            // involution on low 3 bits
      async_copy16(W2b + (size_t)(h * 128 + row) * DMID + n0 + g * 8, &W2s[id * 8]);
    }
  };
  stageW2(0);

  // mish -> bf16 -> Hl
#pragma unroll
  for (int nt = 0; nt < 4; ++nt) {
    int kc = wn * 64 + nt * 16 + (lane & 15);   // local k' in [0,128)
    float bias = b1[n0 + kc];
#pragma unroll
    for (int mt = 0; mt < 4; ++mt) {
#pragma unroll
      for (int r = 0; r < 4; ++r) {
        int ml = wm * 64 + mt * 16 + ((lane >> 4) << 2) + r;
        float x = acc[mt][nt][r] + bias;
        // mish(x) = x*tanh(softplus(x)) = x*u/(u+2), u = t(t+2), t = e^x
        float t = __expf(x);
        float u = t * (t + 2.f);
        float y = (x < 10.f) ? x * u * __builtin_amdgcn_rcpf(u + 2.f) : x;
        int g = kc >> 3;
        Hl[ml * 128 + ((g ^ (ml & 7)) << 3) + (kc & 7)] = (unsigned short)f2bf(y);
      }
    }
  }
  __syncthreads();  // Hl written; W2 half-0 DMA drained; segl visible

  int s0 = segl[0], s1 = segl[127];
  int myseg[16];
#pragma unroll
  for (int mt = 0; mt < 4; ++mt)
#pragma unroll
    for (int r = 0; r < 4; ++r)
      myseg[mt * 4 + r] = segl[wm * 64 + mt * 16 + ((lane >> 4) << 2) + r];

  for (int h = 0; h < 2; ++h) {
    f32x4 acc2[4][4];
#pragma unroll
    for (int i = 0; i < 4; i++)
#pragma unroll
      for (int jj = 0; jj < 4; jj++) acc2[i][jj] = f32x4{0.f, 0.f, 0.f, 0.f};

#pragma unroll
    for (int ks = 0; ks < 4; ++ks) {
      bf16x8 af[4], bg[4];
#pragma unroll
      for (int mt = 0; mt < 4; ++mt) {
        int m = wm * 64 + mt * 16 + (lane & 15);
        int jj = (lane >> 4) + ks * 4;
        af[mt] = *(const bf16x8*)&Hl[m * 128 + ((jj ^ (m & 7)) << 3)];
      }
#pragma unroll
      for (int ot = 0; ot < 4; ++ot) {
        int o = wn * 64 + ot * 16 + (lane & 15);
        int jj = (lane >> 4) + ks * 4;
        bg[ot] = *(const bf16x8*)&W2s[o * 128 + ((jj ^ (o & 7)) << 3)];
      }
#pragma unroll
      for (int mt = 0; mt < 4; ++mt)
#pragma unroll
        for (int ot = 0; ot < 4; ++ot)
          acc2[mt][ot] = __builtin_amdgcn_mfma_f32_16x16x32_bf16(
              af[mt], bg[ot], acc2[mt][ot], 0, 0, 0);
    }

    if (h == 0) {
      __syncthreads();  // all waves done reading W2s half-0
      stageW2(1);       // prefetch half-1 under the atomics below
    }

    // segment-pooled reduction for this o-half (b2 added once: only n0==0 blocks)
    if (s0 == s1) {
      float* op = out + s0 * DOUT + h * 128;
#pragma unroll
      for (int ot = 0; ot < 4; ++ot) {
        int oc = wn * 64 + ot * 16 + (lane & 15);
        float s = (n0 == 0) ? 16.f * b2[h * 128 + oc] : 0.f;
#pragma unroll
        for (int mt = 0; mt < 4; ++mt)
#pragma unroll
          for (int r = 0; r < 4; ++r) s += acc2[mt][ot][r];
        s += __shfl_xor(s, 16);
        s += __shfl_xor(s, 32);
        if ((lane >> 4) == 0) atomicAdd(&op[oc], s);
      }
    } else {
      for (int sgi = s0; sgi <= s1; ++sgi) {
#pragma unroll
        for (int ot = 0; ot < 4; ++ot) {
          int oc = wn * 64 + ot * 16 + (lane & 15);
          float bias2 = (n0 == 0) ? b2[h * 128 + oc] : 0.f;
          float v = 0.f;
#pragma unroll
          for (int mt = 0; mt < 4; ++mt)
#pragma unroll
            for (int r = 0; r < 4; ++r)
              v += (myseg[mt * 4 + r] == sgi) ? (acc2[mt][ot][r] + bias2) : 0.f;
          v += __shfl_xor(v, 16);
          v += __shfl_xor(v, 32);
          if ((lane >> 4) == 0) atomicAdd(&out[sgi * DOUT + h * 128 + oc], v);
        }
      }
    }

    if (h == 0) __syncthreads();  // W2 half-1 DMA drained before h=1 compute
  }
}

extern "C" void kernel_launch(void* const* d_in, const int* in_sizes, int n_in,
                              void* d_out, int out_size, void* d_ws, size_t ws_size,
                              hipStream_t stream) {
  const float* hidden = (const float*)d_in[0];
  const float* W1 = (const float*)d_in[1];
  const float* b1 = (const float*)d_in[2];
  const float* W2 = (const float*)d_in[3];
  const float* b2 = (const float*)d_in[4];
  const int* flat_idx = (const int*)d_in[5];
  const int* seg = (const int*)d_in[6];
  float* out = (float*)d_out;

  unsigned short* W1b = (unsigned short*)d_ws;       // 1024*2048*2 = 4 MiB
  unsigned short* W2b = W1b + (size_t)DMID * H_DIM;  // 256*1024*2  = 512 KiB

  size_t need = ((size_t)DMID * H_DIM + (size_t)DOUT * DMID) * 2;
  if (ws_size < need) return;

  constexpr int N4_1 = DMID * H_DIM / 4;
  constexpr int N4_T = N4_1 + DOUT * DMID / 4;

  hipMemsetAsync(d_out, 0, (size_t)NIMG * DOUT * sizeof(float), stream);
  convert_ws<<<(N4_T + 255) / 256, 256, 0, stream>>>(W1, W2, W1b, N4_1, N4_T);
  gemm_fused<<<2048, 256, 0, stream>>>(hidden, W1b, b1, flat_idx, W2b, b2, seg, out);
}

// Round 7
// 556.274 us; speedup vs baseline: 1.0898x; 1.0203x over previous
//
#include <hip/hip_runtime.h>

#define H_DIM 2048
#define DMID  1024
#define DOUT  256
#define NTOK  32768
#define NIMG  32

typedef __attribute__((ext_vector_type(8))) __bf16 bf16x8;
typedef __attribute__((ext_vector_type(4))) float f32x4;

__device__ __forceinline__ unsigned f2bf(float f) {
  unsigned u = __builtin_bit_cast(unsigned, f);
  u += 0x7fff + ((u >> 16) & 1);   // RNE
  return u >> 16;
}

// Native packed f32->bf16 (RNE) — one VOP3 instead of ~6 VALU ops per pair.
__device__ __forceinline__ unsigned cvtpk(float lo, float hi) {
  unsigned r;
  asm("v_cvt_pk_bf16_f32 %0, %1, %2" : "=v"(r) : "v"(lo), "v"(hi));
  return r;
}

// Forced-hoist global load: volatile asm with explicit reg outputs. The
// register allocator MUST keep d live from issue to use, and volatile
// ordering pins the issue site — hipcc cannot sink it (it sank plain C++
// loads in both prior rounds despite sched_barrier; VGPR stayed 88).
__device__ __forceinline__ void gload4(float4& d, const float* p) {
  asm volatile("global_load_dwordx4 %0, %1, off" : "=v"(d) : "v"(p));
}

// async global->LDS, 16B per lane. LDS dest must be wave-uniform base + lane*16.
__device__ __forceinline__ void async_copy16(const void* gptr, void* lptr) {
  auto g = (const __attribute__((address_space(1))) unsigned int*)(unsigned long long)gptr;
  unsigned loff = (unsigned)(unsigned long long)lptr;
  auto l = (__attribute__((address_space(3))) unsigned int*)loff;
  __builtin_amdgcn_global_load_lds(g, l, 16, 0, 0);
}

// One kernel converts both weight matrices (W1b and W2b are adjacent in ws).
__global__ void convert_ws(const float* __restrict__ W1, const float* __restrict__ W2,
                           unsigned short* __restrict__ dst, int n4_1, int n4_tot) {
  int i = blockIdx.x * blockDim.x + threadIdx.x;
  if (i >= n4_tot) return;
  float4 f = (i < n4_1) ? ((const float4*)W1)[i] : ((const float4*)W2)[i - n4_1];
  ushort4 o;
  o.x = (unsigned short)f2bf(f.x);
  o.y = (unsigned short)f2bf(f.y);
  o.z = (unsigned short)f2bf(f.z);
  o.w = (unsigned short)f2bf(f.w);
  ((ushort4*)dst)[i] = o;
}

// Fully fused single GEMM kernel:
//   H-tile = mish(gather(A32)@W1^T + b1)  (A gathered+converted inline)
//   out[seg[m],o] += H-tile @ W2slice^T  (+ b2 once, gated on n0==0)
// K-loop schedule (per tile): issue 8 asm A-loads -> issue 4 B gload_lds ->
// MFMA(buf cur) -> s_waitcnt vmcnt(4) [A done, B in flight] -> sched_barrier
// -> packA(cvtpk+ds_write to cur^1) -> __syncthreads (drains B DMA).
__global__ __launch_bounds__(256, 2) void gemm_fused(
    const float* __restrict__ A32, const unsigned short* __restrict__ B,
    const float* __restrict__ b1, const int* __restrict__ flat_idx,
    const unsigned short* __restrict__ W2b, const float* __restrict__ b2,
    const int* __restrict__ seg, float* __restrict__ out) {
  __shared__ __align__(16) unsigned short As[2][128 * 64];  // K-loop A dbuf; epilogue: H 128x128
  __shared__ __align__(16) unsigned short Bs[2][128 * 64];  // K-loop B dbuf; epilogue: W2 128x128 half
  __shared__ int rowmap[128];
  __shared__ int segl[128];

  const int tid = threadIdx.x;
  const int lane = tid & 63;
  const int wave = tid >> 6;
  const int wm = wave >> 1, wn = wave & 1;
  // XCD-clustered decomposition: 8 sibling n-blocks of one m-panel adjacent on one XCD,
  // so the fp32 A-panel is fetched from HBM once and L2-hit 7 times.
  const int bid = blockIdx.x;
  const int xcd = bid & 7;
  const int jj0 = bid >> 3;
  const int m0 = (xcd * 32 + (jj0 >> 3)) * 128;
  const int n0 = (jj0 & 7) * 128;

  if (tid < 128) rowmap[tid] = flat_idx[m0 + tid];
  __syncthreads();

  // Hoist per-thread A addresses (row fixed across K-tiles).
  const float* aptr[4];
#pragma unroll
  for (int it = 0; it < 4; ++it) {
    int id = it * 256 + tid;
    int row = id >> 3, c8 = id & 7;
    int gc8 = c8 ^ (row & 7);
    aptr[it] = A32 + (size_t)rowmap[row] * H_DIM + gc8 * 8;
  }

  auto stageB = [&](int b, int t) {
    int kk = t * 64;
#pragma unroll
    for (int it = 0; it < 4; ++it) {
      int id = it * 256 + tid;
      int row = id >> 3, c8 = id & 7;
      int gc8 = c8 ^ (row & 7);
      async_copy16(B + (size_t)(n0 + row) * H_DIM + kk + gc8 * 8, &Bs[b][id * 8]);
    }
  };

  float4 fa[4], fb[4];
  auto loadA = [&](int t) {   // MUST be issued before stageB (vmcnt counting)
    int kk = t * 64;
#pragma unroll
    for (int it = 0; it < 4; ++it) {
      gload4(fa[it], aptr[it] + kk);
      gload4(fb[it], aptr[it] + kk + 4);
    }
  };
  auto packA = [&](int b) {
#pragma unroll
    for (int it = 0; it < 4; ++it) {
      int id = it * 256 + tid;
      uint4 pk;
      pk.x = cvtpk(fa[it].x, fa[it].y);
      pk.y = cvtpk(fa[it].z, fa[it].w);
      pk.z = cvtpk(fb[it].x, fb[it].y);
      pk.w = cvtpk(fb[it].z, fb[it].w);
      *(uint4*)&As[b][id * 8] = pk;
    }
  };

  f32x4 acc[4][4];
#pragma unroll
  for (int i = 0; i < 4; i++)
#pragma unroll
    for (int jj = 0; jj < 4; jj++) acc[i][jj] = f32x4{0.f, 0.f, 0.f, 0.f};

  constexpr int NT = H_DIM / 64;  // 32 K-tiles
  // prologue: tile 0
  loadA(0);                 // vmcnt +8 (oldest)
  stageB(0, 0);             // vmcnt +4
  asm volatile("s_waitcnt vmcnt(4)" ::: "memory");  // A done, B in flight
  __builtin_amdgcn_sched_barrier(0);
  packA(0);
  __syncthreads();

  int cur = 0;
  for (int t = 0; t < NT; ++t) {
    if (t + 1 < NT) {
      loadA(t + 1);             // 8 asm loads first (deepest latency, oldest in queue)
      stageB(cur ^ 1, t + 1);   // 4 DMA ops, drained at the barrier
    }
#pragma unroll
    for (int ks = 0; ks < 2; ++ks) {
      bf16x8 af[4], bg[4];
#pragma unroll
      for (int mt = 0; mt < 4; ++mt) {
        int r = wm * 64 + mt * 16 + (lane & 15);
        int jj = (lane >> 4) + ks * 4;
        af[mt] = *(const bf16x8*)&As[cur][r * 64 + ((jj ^ (r & 7)) << 3)];
      }
#pragma unroll
      for (int nt = 0; nt < 4; ++nt) {
        int r = wn * 64 + nt * 16 + (lane & 15);
        int jj = (lane >> 4) + ks * 4;
        bg[nt] = *(const bf16x8*)&Bs[cur][r * 64 + ((jj ^ (r & 7)) << 3)];
      }
#pragma unroll
      for (int mt = 0; mt < 4; ++mt)
#pragma unroll
        for (int nt = 0; nt < 4; ++nt)
          acc[mt][nt] = __builtin_amdgcn_mfma_f32_16x16x32_bf16(
              af[mt], bg[nt], acc[mt][nt], 0, 0, 0);
    }
    if (t + 1 < NT) {
      asm volatile("s_waitcnt vmcnt(4)" ::: "memory");  // A-loads complete; B-DMA still in flight
      __builtin_amdgcn_sched_barrier(0);                // rule #18: nothing hoists above the wait
      packA(cur ^ 1);
    }
    __syncthreads();
    cur ^= 1;
  }

  // ================= fused epilogue =================
  // Hl: 128(m) x 128(k') bf16, swizzled [m*128 + ((g^(m&7))<<3) + (k&7)], g=k>>3
  // W2s: 128(o-half) x 128(k') bf16, same swizzle, staged async per 128-o half.
  unsigned short* Hl  = &As[0][0];   // 32 KiB (spans both dbuf halves)
  unsigned short* W2s = &Bs[0][0];   // 32 KiB

  if (tid < 128) segl[tid] = seg[m0 + tid];

  auto stageW2 = [&](int h) {
#pragma unroll
    for (int it = 0; it < 8; ++it) {
      int id = it * 256 + tid;            // 0..2047 granules of 16B
      int row = id >> 4, c16 = id & 15;
      int g = c16 ^ (row & 7);            // involution on low 3 bits
      async_copy16(W2b + (size_t)(h * 128 + row) * DMID + n0 + g * 8, &W2s[id * 8]);
    }
  };
  stageW2(0);

  // mish -> bf16 -> Hl
#pragma unroll
  for (int nt = 0; nt < 4; ++nt) {
    int kc = wn * 64 + nt * 16 + (lane & 15);   // local k' in [0,128)
    float bias = b1[n0 + kc];
#pragma unroll
    for (int mt = 0; mt < 4; ++mt) {
#pragma unroll
      for (int r = 0; r < 4; ++r) {
        int ml = wm * 64 + mt * 16 + ((lane >> 4) << 2) + r;
        float x = acc[mt][nt][r] + bias;
        // mish(x) = x*tanh(softplus(x)) = x*u/(u+2), u = t(t+2), t = e^x
        float t = __expf(x);
        float u = t * (t + 2.f);
        float y = (x < 10.f) ? x * u * __builtin_amdgcn_rcpf(u + 2.f) : x;
        int g = kc >> 3;
        Hl[ml * 128 + ((g ^ (ml & 7)) << 3) + (kc & 7)] = (unsigned short)f2bf(y);
      }
    }
  }
  __syncthreads();  // Hl written; W2 half-0 DMA drained; segl visible

  int s0 = segl[0], s1 = segl[127];
  int myseg[16];
#pragma unroll
  for (int mt = 0; mt < 4; ++mt)
#pragma unroll
    for (int r = 0; r < 4; ++r)
      myseg[mt * 4 + r] = segl[wm * 64 + mt * 16 + ((lane >> 4) << 2) + r];

  for (int h = 0; h < 2; ++h) {
    f32x4 acc2[4][4];
#pragma unroll
    for (int i = 0; i < 4; i++)
#pragma unroll
      for (int jj = 0; jj < 4; jj++) acc2[i][jj] = f32x4{0.f, 0.f, 0.f, 0.f};

#pragma unroll
    for (int ks = 0; ks < 4; ++ks) {
      bf16x8 af[4], bg[4];
#pragma unroll
      for (int mt = 0; mt < 4; ++mt) {
        int m = wm * 64 + mt * 16 + (lane & 15);
        int jj = (lane >> 4) + ks * 4;
        af[mt] = *(const bf16x8*)&Hl[m * 128 + ((jj ^ (m & 7)) << 3)];
      }
#pragma unroll
      for (int ot = 0; ot < 4; ++ot) {
        int o = wn * 64 + ot * 16 + (lane & 15);
        int jj = (lane >> 4) + ks * 4;
        bg[ot] = *(const bf16x8*)&W2s[o * 128 + ((jj ^ (o & 7)) << 3)];
      }
#pragma unroll
      for (int mt = 0; mt < 4; ++mt)
#pragma unroll
        for (int ot = 0; ot < 4; ++ot)
          acc2[mt][ot] = __builtin_amdgcn_mfma_f32_16x16x32_bf16(
              af[mt], bg[ot], acc2[mt][ot], 0, 0, 0);
    }

    if (h == 0) {
      __syncthreads();  // all waves done reading W2s half-0
      stageW2(1);       // prefetch half-1 under the atomics below
    }

    // segment-pooled reduction for this o-half (b2 added once: only n0==0 blocks)
    if (s0 == s1) {
      float* op = out + s0 * DOUT + h * 128;
#pragma unroll
      for (int ot = 0; ot < 4; ++ot) {
        int oc = wn * 64 + ot * 16 + (lane & 15);
        float s = (n0 == 0) ? 16.f * b2[h * 128 + oc] : 0.f;
#pragma unroll
        for (int mt = 0; mt < 4; ++mt)
#pragma unroll
          for (int r = 0; r < 4; ++r) s += acc2[mt][ot][r];
        s += __shfl_xor(s, 16);
        s += __shfl_xor(s, 32);
        if ((lane >> 4) == 0) atomicAdd(&op[oc], s);
      }
    } else {
      for (int sgi = s0; sgi <= s1; ++sgi) {
#pragma unroll
        for (int ot = 0; ot < 4; ++ot) {
          int oc = wn * 64 + ot * 16 + (lane & 15);
          float bias2 = (n0 == 0) ? b2[h * 128 + oc] : 0.f;
          float v = 0.f;
#pragma unroll
          for (int mt = 0; mt < 4; ++mt)
#pragma unroll
            for (int r = 0; r < 4; ++r)
              v += (myseg[mt * 4 + r] == sgi) ? (acc2[mt][ot][r] + bias2) : 0.f;
          v += __shfl_xor(v, 16);
          v += __shfl_xor(v, 32);
          if ((lane >> 4) == 0) atomicAdd(&out[sgi * DOUT + h * 128 + oc], v);
        }
      }
    }

    if (h == 0) __syncthreads();  // W2 half-1 DMA drained before h=1 compute
  }
}

extern "C" void kernel_launch(void* const* d_in, const int* in_sizes, int n_in,
                              void* d_out, int out_size, void* d_ws, size_t ws_size,
                              hipStream_t stream) {
  const float* hidden = (const float*)d_in[0];
  const float* W1 = (const float*)d_in[1];
  const float* b1 = (const float*)d_in[2];
  const float* W2 = (const float*)d_in[3];
  const float* b2 = (const float*)d_in[4];
  const int* flat_idx = (const int*)d_in[5];
  const int* seg = (const int*)d_in[6];
  float* out = (float*)d_out;

  unsigned short* W1b = (unsigned short*)d_ws;       // 1024*2048*2 = 4 MiB
  unsigned short* W2b = W1b + (size_t)DMID * H_DIM;  // 256*1024*2  = 512 KiB

  size_t need = ((size_t)DMID * H_DIM + (size_t)DOUT * DMID) * 2;
  if (ws_size < need) return;

  constexpr int N4_1 = DMID * H_DIM / 4;
  constexpr int N4_T = N4_1 + DOUT * DMID / 4;

  hipMemsetAsync(d_out, 0, (size_t)NIMG * DOUT * sizeof(float), stream);
  convert_ws<<<(N4_T + 255) / 256, 256, 0, stream>>>(W1, W2, W1b, N4_1, N4_T);
  gemm_fused<<<2048, 256, 0, stream>>>(hidden, W1b, b1, flat_idx, W2b, b2, seg, out);
}